// Round 18
// baseline (58.274 us; speedup 1.0000x reference)
//
#include <hip/hip_runtime.h>
#include <hip/hip_fp16.h>

#define N_NODES 100000
#define N_EDGES 1000000
#define D_FEAT  64

// Binning: 64 consecutive dst nodes per bin
#define BIN_SHIFT 6
#define BIN_NODES 64
#define NBINS ((N_NODES + BIN_NODES - 1) >> BIN_SHIFT)   // 1563
#define BIN_CAP 1152    // bin total ~Poisson(640), 20 sigma headroom

// Dense single-pass partition: 256 chunks; each block LDS-histograms its
// ~3907 edges, scans, and places them into ONE dense run region per chunk.
// No cells, no holes, no overflow (region sized to the chunk).
#define NCHUNK 256
#define CHUNK_E ((N_EDGES + NCHUNK - 1) / NCHUNK)   // 3907
#define PCHUNK 3968                                  // padded region (ints)
#define CONV4 (N_NODES * D_FEAT / 4 / NCHUNK)        // 6250 float4 per block

// ---------------------------------------------------------------------------
// Workspace layout (ints):
//   CNT    u16 [NBINS][NCHUNK]  per-(bin,chunk) run length    (800 KB)
//   PF     u16 [NBINS][NCHUNK]  exclusive prefix within chunk (800 KB)
//   bucket [NCHUNK][PCHUNK]     packed (local_dst<<17)|src, dense (4.1 MB)
//   emb16  [N_NODES*D_FEAT] __half                            (12.8 MB)
// ---------------------------------------------------------------------------
#define WS_CNT    0
#define WS_PF     (NBINS * NCHUNK / 2)
#define WS_BUCKET (NBINS * NCHUNK)
#define WS_EMB16  (WS_BUCKET + NCHUNK * PCHUNK)
#define WS_NEEDED ((size_t)(WS_EMB16 + (size_t)N_NODES * D_FEAT / 2) * sizeof(int))

// K1: every block partitions its chunk (LDS hist -> scan -> dense place),
// then converts its contiguous slice of emb f32 -> fp16. All 256 CUs busy.
__global__ __launch_bounds__(1024) void prep_kernel(const float* __restrict__ emb,
                                                    const int* __restrict__ src,
                                                    const int* __restrict__ dst,
                                                    int* __restrict__ ws) {
    __shared__ int h[NBINS];                 // hist -> prefix -> cursor
    int tid = threadIdx.x;
    int c   = blockIdx.x;
    for (int j = tid; j < NBINS; j += 1024) h[j] = 0;
    __syncthreads();

    int e0 = c * CHUNK_E, e1 = min(N_EDGES, e0 + CHUNK_E);
    // pass A: histogram dst bins (LDS atomics)
    for (int e = e0 + tid; e < e1; e += 1024)
        atomicAdd(&h[dst[e] >> BIN_SHIFT], 1);
    __syncthreads();

    // write run lengths (transposed u16: gather reads coalesced rows)
    unsigned short* CNT = (unsigned short*)(ws + WS_CNT);
    for (int j = tid; j < NBINS; j += 1024)
        CNT[j * NCHUNK + c] = (unsigned short)h[j];
    __syncthreads();

    // wave 0: exclusive scan of h in place
    if (tid < 64) {
        int lane = tid, carry = 0;
        for (int cb = 0; cb < NBINS; cb += 64) {
            int idx = cb + lane;
            int v = (idx < NBINS) ? h[idx] : 0;
            int incl = v;
            #pragma unroll
            for (int o = 1; o < 64; o <<= 1) {
                int t = __shfl_up(incl, o);
                if (lane >= o) incl += t;
            }
            if (idx < NBINS) h[idx] = carry + incl - v;
            carry += __shfl(incl, 63);
        }
    }
    __syncthreads();

    unsigned short* PF = (unsigned short*)(ws + WS_PF);
    for (int j = tid; j < NBINS; j += 1024)
        PF[j * NCHUNK + c] = (unsigned short)h[j];
    __syncthreads();

    // pass B: re-read edges (L2-hot), place into dense region; h = cursors
    int* __restrict__ run = ws + WS_BUCKET + c * PCHUNK;
    for (int e = e0 + tid; e < e1; e += 1024) {
        int d = dst[e], s = src[e];
        int slot = atomicAdd(&h[d >> BIN_SHIFT], 1);
        run[slot] = ((d & (BIN_NODES - 1)) << 17) | s;
    }

    // conversion: contiguous slice, f32 -> fp16 (no sync needed; independent)
    {
        __half2* __restrict__ e16 = (__half2*)(ws + WS_EMB16);
        const float4* __restrict__ e32 = (const float4*)emb;
        int st = c * CONV4;
        for (int i = st + tid; i < st + CONV4; i += 1024) {
            float4 v = e32[i];
            e16[2 * i]     = __floats2half2_rn(v.x, v.y);
            e16[2 * i + 1] = __floats2half2_rn(v.z, v.w);
        }
    }
}

// K2: per-bin gather (fp16 rows) — R15's proven structure with dense runs.
// Stage the bin's 256 runs into LDS via bump allocator (+histogram),
// counting-sort by local dst, then gather: 8 waves x 8 nodes in PAIRS;
// 16-lane group per row, lane loads 8B (4 halves) -> f32 accumulate;
// 6 guarded tail loads in flight; shfl_xor reduce across 4 edge subgroups.
__global__ __launch_bounds__(512) void fused_gather_kernel(const int* __restrict__ ws,
                                                           float* __restrict__ out) {
    __shared__ int s_edges[BIN_CAP];
    __shared__ int s_sorted[BIN_CAP];
    __shared__ int s_rcnt[NCHUNK];
    __shared__ int s_roff[NCHUNK];
    __shared__ int s_rbase[NCHUNK];
    __shared__ int s_hist[BIN_NODES];
    __shared__ int s_off[BIN_NODES];
    __shared__ int s_cur[BIN_NODES];
    __shared__ int s_alloc;

    const char* __restrict__ emb16 = (const char*)(ws + WS_EMB16);
    int b   = blockIdx.x;
    int tid = threadIdx.x;

    if (tid < BIN_NODES) s_hist[tid] = 0;
    if (tid == 0) s_alloc = 0;
    __syncthreads();

    // phase 1: threads 0..255 read run length + prefix (coalesced u16 rows)
    if (tid < NCHUNK) {
        const unsigned short* CNT = (const unsigned short*)(ws + WS_CNT);
        const unsigned short* PF  = (const unsigned short*)(ws + WS_PF);
        int cnt = (int)CNT[b * NCHUNK + tid];
        int pf  = (int)PF[b * NCHUNK + tid];
        s_rcnt[tid]  = cnt;
        s_rbase[tid] = tid * PCHUNK + pf;
        s_roff[tid]  = atomicAdd(&s_alloc, cnt);
    }
    __syncthreads();
    int total = s_alloc;
    if (total > BIN_CAP) total = BIN_CAP;

    // phase 2: 2 threads per run copy entries + histogram
    {
        int g = tid >> 1, li = tid & 1;
        int cg = s_rcnt[g], og = s_roff[g];
        const int* __restrict__ run = ws + WS_BUCKET + s_rbase[g];
        for (int i = li; i < cg; i += 2) {
            int o = og + i;
            if (o < BIN_CAP) {
                int p = run[i];
                s_edges[o] = p;
                atomicAdd(&s_hist[p >> 17], 1);
            }
        }
    }
    __syncthreads();

    // scan 64 hist entries with wave 0
    if (tid < 64) {
        int v = s_hist[tid];
        int incl = v;
        #pragma unroll
        for (int o = 1; o < 64; o <<= 1) {
            int t = __shfl_up(incl, o);
            if (tid >= o) incl += t;
        }
        s_off[tid] = incl - v;
        s_cur[tid] = incl - v;
    }
    __syncthreads();

    // counting-sort scatter within LDS
    for (int i = tid; i < total; i += 512) {
        int p = s_edges[i];
        s_sorted[atomicAdd(&s_cur[p >> 17], 1)] = p & 0x1FFFF;
    }
    __syncthreads();

    // gather: 8 waves x 8 nodes in 4 pairs; sub = edge slot, fq = 8B index
    int wave = tid >> 6, lane = tid & 63;
    int sub  = lane >> 4;
    int fq   = lane & 15;
    const int fb = fq << 3;          // byte offset of this lane's 8B in a row

    #pragma unroll
    for (int pr = 0; pr < 4; ++pr) {
        int lnA = wave * 8 + pr * 2;
        int lnB = lnA + 1;
        int degA = s_hist[lnA], offA = s_off[lnA];
        int degB = s_hist[lnB], offB = s_off[lnB];

        float4 accA = make_float4(0.f, 0.f, 0.f, 0.f);
        float4 accB = make_float4(0.f, 0.f, 0.f, 0.f);

        int iA = sub, iB = sub;
        // main loops (deg > 15; rare): 4 rows in flight
        for (; iA + 12 < degA; iA += 16) {
            uint2 u0 = *(const uint2*)(emb16 + ((size_t)s_sorted[offA + iA]      << 7) + fb);
            uint2 u1 = *(const uint2*)(emb16 + ((size_t)s_sorted[offA + iA + 4]  << 7) + fb);
            uint2 u2 = *(const uint2*)(emb16 + ((size_t)s_sorted[offA + iA + 8]  << 7) + fb);
            uint2 u3 = *(const uint2*)(emb16 + ((size_t)s_sorted[offA + iA + 12] << 7) + fb);
            float2 f;
            f = __half22float2(*(__half2*)&u0.x); accA.x += f.x; accA.y += f.y;
            f = __half22float2(*(__half2*)&u0.y); accA.z += f.x; accA.w += f.y;
            f = __half22float2(*(__half2*)&u1.x); accA.x += f.x; accA.y += f.y;
            f = __half22float2(*(__half2*)&u1.y); accA.z += f.x; accA.w += f.y;
            f = __half22float2(*(__half2*)&u2.x); accA.x += f.x; accA.y += f.y;
            f = __half22float2(*(__half2*)&u2.y); accA.z += f.x; accA.w += f.y;
            f = __half22float2(*(__half2*)&u3.x); accA.x += f.x; accA.y += f.y;
            f = __half22float2(*(__half2*)&u3.y); accA.z += f.x; accA.w += f.y;
        }
        for (; iB + 12 < degB; iB += 16) {
            uint2 u0 = *(const uint2*)(emb16 + ((size_t)s_sorted[offB + iB]      << 7) + fb);
            uint2 u1 = *(const uint2*)(emb16 + ((size_t)s_sorted[offB + iB + 4]  << 7) + fb);
            uint2 u2 = *(const uint2*)(emb16 + ((size_t)s_sorted[offB + iB + 8]  << 7) + fb);
            uint2 u3 = *(const uint2*)(emb16 + ((size_t)s_sorted[offB + iB + 12] << 7) + fb);
            float2 f;
            f = __half22float2(*(__half2*)&u0.x); accB.x += f.x; accB.y += f.y;
            f = __half22float2(*(__half2*)&u0.y); accB.z += f.x; accB.w += f.y;
            f = __half22float2(*(__half2*)&u1.x); accB.x += f.x; accB.y += f.y;
            f = __half22float2(*(__half2*)&u1.y); accB.z += f.x; accB.w += f.y;
            f = __half22float2(*(__half2*)&u2.x); accB.x += f.x; accB.y += f.y;
            f = __half22float2(*(__half2*)&u2.y); accB.z += f.x; accB.w += f.y;
            f = __half22float2(*(__half2*)&u3.x); accB.x += f.x; accB.y += f.y;
            f = __half22float2(*(__half2*)&u3.y); accB.z += f.x; accB.w += f.y;
        }
        // tails: up to 6 independent guarded loads, all issued before use
        {
            uint2 a0 = make_uint2(0u, 0u), a1 = a0, a2 = a0;
            uint2 b0 = a0, b1 = a0, b2 = a0;
            if (iA < degA)     a0 = *(const uint2*)(emb16 + ((size_t)s_sorted[offA + iA]     << 7) + fb);
            if (iA + 4 < degA) a1 = *(const uint2*)(emb16 + ((size_t)s_sorted[offA + iA + 4] << 7) + fb);
            if (iA + 8 < degA) a2 = *(const uint2*)(emb16 + ((size_t)s_sorted[offA + iA + 8] << 7) + fb);
            if (iB < degB)     b0 = *(const uint2*)(emb16 + ((size_t)s_sorted[offB + iB]     << 7) + fb);
            if (iB + 4 < degB) b1 = *(const uint2*)(emb16 + ((size_t)s_sorted[offB + iB + 4] << 7) + fb);
            if (iB + 8 < degB) b2 = *(const uint2*)(emb16 + ((size_t)s_sorted[offB + iB + 8] << 7) + fb);
            float2 f;
            f = __half22float2(*(__half2*)&a0.x); accA.x += f.x; accA.y += f.y;
            f = __half22float2(*(__half2*)&a0.y); accA.z += f.x; accA.w += f.y;
            f = __half22float2(*(__half2*)&a1.x); accA.x += f.x; accA.y += f.y;
            f = __half22float2(*(__half2*)&a1.y); accA.z += f.x; accA.w += f.y;
            f = __half22float2(*(__half2*)&a2.x); accA.x += f.x; accA.y += f.y;
            f = __half22float2(*(__half2*)&a2.y); accA.z += f.x; accA.w += f.y;
            f = __half22float2(*(__half2*)&b0.x); accB.x += f.x; accB.y += f.y;
            f = __half22float2(*(__half2*)&b0.y); accB.z += f.x; accB.w += f.y;
            f = __half22float2(*(__half2*)&b1.x); accB.x += f.x; accB.y += f.y;
            f = __half22float2(*(__half2*)&b1.y); accB.z += f.x; accB.w += f.y;
            f = __half22float2(*(__half2*)&b2.x); accB.x += f.x; accB.y += f.y;
            f = __half22float2(*(__half2*)&b2.y); accB.z += f.x; accB.w += f.y;
        }

        // reduce both across the 4 edge subgroups (independent chains)
        #pragma unroll
        for (int m = 16; m < 64; m <<= 1) {
            accA.x += __shfl_xor(accA.x, m);  accB.x += __shfl_xor(accB.x, m);
            accA.y += __shfl_xor(accA.y, m);  accB.y += __shfl_xor(accB.y, m);
            accA.z += __shfl_xor(accA.z, m);  accB.z += __shfl_xor(accB.z, m);
            accA.w += __shfl_xor(accA.w, m);  accB.w += __shfl_xor(accB.w, m);
        }

        if (sub == 0) {
            int nodeA = (b << BIN_SHIFT) + lnA;
            int nodeB = (b << BIN_SHIFT) + lnB;
            float invA = 1.0f / (float)max(degA, 1);
            float invB = 1.0f / (float)max(degB, 1);
            accA.x *= invA; accA.y *= invA; accA.z *= invA; accA.w *= invA;
            accB.x *= invB; accB.y *= invB; accB.z *= invB; accB.w *= invB;
            if (nodeA < N_NODES)
                *(float4*)(out + (size_t)nodeA * D_FEAT + fq * 4) = accA;
            if (nodeB < N_NODES)
                *(float4*)(out + (size_t)nodeB * D_FEAT + fq * 4) = accB;
        }
    }
}

// ======================= Fallback (R1 atomic path) =========================

__global__ void gcn_zero_kernel(float* __restrict__ out, float* __restrict__ counts) {
    int stride = gridDim.x * blockDim.x;
    int i = blockIdx.x * blockDim.x + threadIdx.x;
    const int total = N_NODES * D_FEAT;
    for (int idx = i; idx < total; idx += stride) out[idx] = 0.0f;
    for (int idx = i; idx < N_NODES; idx += stride) counts[idx] = 0.0f;
}

__global__ void gcn_scatter_kernel(const float* __restrict__ emb,
                                   const int* __restrict__ src,
                                   const int* __restrict__ dst,
                                   float* __restrict__ out,
                                   float* __restrict__ counts) {
    int gid  = blockIdx.x * blockDim.x + threadIdx.x;
    int edge = gid >> 6;
    int lane = gid & 63;
    if (edge >= N_EDGES) return;
    int s = src[edge];
    int d = dst[edge];
    float v = emb[(size_t)s * D_FEAT + lane];
    atomicAdd(&out[(size_t)d * D_FEAT + lane], v);
    if (lane == 0) atomicAdd(&counts[d], 1.0f);
}

__global__ void gcn_norm_kernel(float* __restrict__ out,
                                const float* __restrict__ counts) {
    int i = blockIdx.x * blockDim.x + threadIdx.x;
    if (i >= N_NODES * D_FEAT) return;
    int n = i >> 6;
    float c = counts[n];
    out[i] *= (1.0f / fmaxf(c, 1.0f));
}

// ===========================================================================

extern "C" void kernel_launch(void* const* d_in, const int* in_sizes, int n_in,
                              void* d_out, int out_size, void* d_ws, size_t ws_size,
                              hipStream_t stream) {
    const float* emb = (const float*)d_in[0];
    const int*   src = (const int*)d_in[1];
    const int*   dst = (const int*)d_in[2];
    float* out = (float*)d_out;

    if (ws_size >= WS_NEEDED) {
        int* ws = (int*)d_ws;
        prep_kernel<<<NCHUNK, 1024, 0, stream>>>(emb, src, dst, ws);
        fused_gather_kernel<<<NBINS, 512, 0, stream>>>(ws, out);
    } else {
        float* counts = (float*)d_ws;
        gcn_zero_kernel<<<2048, 256, 0, stream>>>(out, counts);
        const int scatter_blocks = (N_EDGES * 64) / 256;
        gcn_scatter_kernel<<<scatter_blocks, 256, 0, stream>>>(emb, src, dst, out, counts);
        const int norm_blocks = (N_NODES * D_FEAT + 255) / 256;
        gcn_norm_kernel<<<norm_blocks, 256, 0, stream>>>(out, counts);
    }
}

// Round 19
// 55.954 us; speedup vs baseline: 1.0415x; 1.0415x over previous
//
#include <hip/hip_runtime.h>
#include <hip/hip_fp16.h>

#define N_NODES 100000
#define N_EDGES 1000000
#define D_FEAT  64

// Binning: 64 consecutive dst nodes per bin
#define BIN_SHIFT 6
#define BIN_NODES 64
#define NBINS ((N_NODES + BIN_NODES - 1) >> BIN_SHIFT)   // 1563
#define BIN_CAP 1152    // bin total ~Poisson(640), 20 sigma headroom

// Dense single-pass partition: 256 chunks; each block LDS-histograms its
// ~3907 edges, scans, and places them into ONE dense run region per chunk.
// No cells, no holes, no overflow (region sized to the chunk).
#define NCHUNK 256
#define CHUNK_E ((N_EDGES + NCHUNK - 1) / NCHUNK)   // 3907
#define PCHUNK 3968                                  // padded region (ints)
#define CONV4 (N_NODES * D_FEAT / 4 / NCHUNK)        // 6250 float4 per block

// ---------------------------------------------------------------------------
// Workspace layout (ints):
//   PFCNT  u32 [NCHUNK][NBINS]  (prefix<<16)|count — contiguous row per
//                               chunk (no write-allocate waste)   (1.6 MB)
//   bucket [NCHUNK][PCHUNK]     packed (local_dst<<17)|src, dense (4.1 MB)
//   emb16  [N_NODES*D_FEAT] __half                               (12.8 MB)
// ---------------------------------------------------------------------------
#define WS_PFCNT  0
#define WS_BUCKET (NCHUNK * NBINS)
#define WS_EMB16  (WS_BUCKET + NCHUNK * PCHUNK)
#define WS_NEEDED ((size_t)(WS_EMB16 + (size_t)N_NODES * D_FEAT / 2) * sizeof(int))

// K1: every block partitions its chunk (LDS hist -> scan -> dense place),
// then converts its contiguous slice of emb f32 -> fp16. All 256 CUs busy.
__global__ __launch_bounds__(1024) void prep_kernel(const float* __restrict__ emb,
                                                    const int* __restrict__ src,
                                                    const int* __restrict__ dst,
                                                    int* __restrict__ ws) {
    __shared__ int h[NBINS];                 // hist -> prefix -> cursor
    int tid = threadIdx.x;
    int c   = blockIdx.x;
    for (int j = tid; j < NBINS; j += 1024) h[j] = 0;
    __syncthreads();

    int e0 = c * CHUNK_E, e1 = min(N_EDGES, e0 + CHUNK_E);
    // pass A: histogram dst bins (LDS atomics)
    for (int e = e0 + tid; e < e1; e += 1024)
        atomicAdd(&h[dst[e] >> BIN_SHIFT], 1);
    __syncthreads();

    // save this thread's counts before the in-place scan (<=2 bins/thread)
    int j0 = tid, j1 = tid + 1024;
    int c0 = (j0 < NBINS) ? h[j0] : 0;
    int c1 = (j1 < NBINS) ? h[j1] : 0;
    __syncthreads();

    // wave 0: exclusive scan of h in place
    if (tid < 64) {
        int lane = tid, carry = 0;
        for (int cb = 0; cb < NBINS; cb += 64) {
            int idx = cb + lane;
            int v = (idx < NBINS) ? h[idx] : 0;
            int incl = v;
            #pragma unroll
            for (int o = 1; o < 64; o <<= 1) {
                int t = __shfl_up(incl, o);
                if (lane >= o) incl += t;
            }
            if (idx < NBINS) h[idx] = carry + incl - v;
            carry += __shfl(incl, 63);
        }
    }
    __syncthreads();

    // write packed (prefix<<16)|count — one contiguous 6.2 KB row
    int* __restrict__ pfcnt = ws + WS_PFCNT + c * NBINS;
    if (j0 < NBINS) pfcnt[j0] = (h[j0] << 16) | c0;
    if (j1 < NBINS) pfcnt[j1] = (h[j1] << 16) | c1;

    // pass B: re-read edges (L2-hot), place into dense region; h = cursors
    int* __restrict__ run = ws + WS_BUCKET + c * PCHUNK;
    for (int e = e0 + tid; e < e1; e += 1024) {
        int d = dst[e], s = src[e];
        int slot = atomicAdd(&h[d >> BIN_SHIFT], 1);
        run[slot] = ((d & (BIN_NODES - 1)) << 17) | s;
    }

    // conversion: contiguous slice, f32 -> fp16 (independent of the above)
    {
        __half2* __restrict__ e16 = (__half2*)(ws + WS_EMB16);
        const float4* __restrict__ e32 = (const float4*)emb;
        int st = c * CONV4;
        for (int i = st + tid; i < st + CONV4; i += 1024) {
            float4 v = e32[i];
            e16[2 * i]     = __floats2half2_rn(v.x, v.y);
            e16[2 * i + 1] = __floats2half2_rn(v.z, v.w);
        }
    }
}

// K2: per-bin gather (fp16 rows) — R15's proven structure with dense runs.
// Stage the bin's 256 runs into LDS via bump allocator (+histogram),
// counting-sort by local dst, then gather: 8 waves x 8 nodes in PAIRS;
// 16-lane group per row, lane loads 8B (4 halves) -> f32 accumulate;
// 6 guarded tail loads in flight; shfl_xor reduce across 4 edge subgroups.
__global__ __launch_bounds__(512) void fused_gather_kernel(const int* __restrict__ ws,
                                                           float* __restrict__ out) {
    __shared__ int s_edges[BIN_CAP];
    __shared__ int s_sorted[BIN_CAP];
    __shared__ int s_rcnt[NCHUNK];
    __shared__ int s_roff[NCHUNK];
    __shared__ int s_rbase[NCHUNK];
    __shared__ int s_hist[BIN_NODES];
    __shared__ int s_off[BIN_NODES];
    __shared__ int s_cur[BIN_NODES];
    __shared__ int s_alloc;

    const char* __restrict__ emb16 = (const char*)(ws + WS_EMB16);
    int b   = blockIdx.x;
    int tid = threadIdx.x;

    if (tid < BIN_NODES) s_hist[tid] = 0;
    if (tid == 0) s_alloc = 0;
    __syncthreads();

    // phase 1: threads 0..255 read packed prefix|count (L2-resident array)
    if (tid < NCHUNK) {
        unsigned pc = (unsigned)ws[WS_PFCNT + tid * NBINS + b];
        int cnt = (int)(pc & 0xFFFFu);
        int pf  = (int)(pc >> 16);
        s_rcnt[tid]  = cnt;
        s_rbase[tid] = tid * PCHUNK + pf;
        s_roff[tid]  = atomicAdd(&s_alloc, cnt);
    }
    __syncthreads();
    int total = s_alloc;
    if (total > BIN_CAP) total = BIN_CAP;

    // phase 2: 2 threads per run copy entries + histogram
    {
        int g = tid >> 1, li = tid & 1;
        int cg = s_rcnt[g], og = s_roff[g];
        const int* __restrict__ run = ws + WS_BUCKET + s_rbase[g];
        for (int i = li; i < cg; i += 2) {
            int o = og + i;
            if (o < BIN_CAP) {
                int p = run[i];
                s_edges[o] = p;
                atomicAdd(&s_hist[p >> 17], 1);
            }
        }
    }
    __syncthreads();

    // scan 64 hist entries with wave 0
    if (tid < 64) {
        int v = s_hist[tid];
        int incl = v;
        #pragma unroll
        for (int o = 1; o < 64; o <<= 1) {
            int t = __shfl_up(incl, o);
            if (tid >= o) incl += t;
        }
        s_off[tid] = incl - v;
        s_cur[tid] = incl - v;
    }
    __syncthreads();

    // counting-sort scatter within LDS
    for (int i = tid; i < total; i += 512) {
        int p = s_edges[i];
        s_sorted[atomicAdd(&s_cur[p >> 17], 1)] = p & 0x1FFFF;
    }
    __syncthreads();

    // gather: 8 waves x 8 nodes in 4 pairs; sub = edge slot, fq = 8B index
    int wave = tid >> 6, lane = tid & 63;
    int sub  = lane >> 4;
    int fq   = lane & 15;
    const int fb = fq << 3;          // byte offset of this lane's 8B in a row

    #pragma unroll
    for (int pr = 0; pr < 4; ++pr) {
        int lnA = wave * 8 + pr * 2;
        int lnB = lnA + 1;
        int degA = s_hist[lnA], offA = s_off[lnA];
        int degB = s_hist[lnB], offB = s_off[lnB];

        float4 accA = make_float4(0.f, 0.f, 0.f, 0.f);
        float4 accB = make_float4(0.f, 0.f, 0.f, 0.f);

        int iA = sub, iB = sub;
        // main loops (deg > 15; rare): 4 rows in flight
        for (; iA + 12 < degA; iA += 16) {
            uint2 u0 = *(const uint2*)(emb16 + ((size_t)s_sorted[offA + iA]      << 7) + fb);
            uint2 u1 = *(const uint2*)(emb16 + ((size_t)s_sorted[offA + iA + 4]  << 7) + fb);
            uint2 u2 = *(const uint2*)(emb16 + ((size_t)s_sorted[offA + iA + 8]  << 7) + fb);
            uint2 u3 = *(const uint2*)(emb16 + ((size_t)s_sorted[offA + iA + 12] << 7) + fb);
            float2 f;
            f = __half22float2(*(__half2*)&u0.x); accA.x += f.x; accA.y += f.y;
            f = __half22float2(*(__half2*)&u0.y); accA.z += f.x; accA.w += f.y;
            f = __half22float2(*(__half2*)&u1.x); accA.x += f.x; accA.y += f.y;
            f = __half22float2(*(__half2*)&u1.y); accA.z += f.x; accA.w += f.y;
            f = __half22float2(*(__half2*)&u2.x); accA.x += f.x; accA.y += f.y;
            f = __half22float2(*(__half2*)&u2.y); accA.z += f.x; accA.w += f.y;
            f = __half22float2(*(__half2*)&u3.x); accA.x += f.x; accA.y += f.y;
            f = __half22float2(*(__half2*)&u3.y); accA.z += f.x; accA.w += f.y;
        }
        for (; iB + 12 < degB; iB += 16) {
            uint2 u0 = *(const uint2*)(emb16 + ((size_t)s_sorted[offB + iB]      << 7) + fb);
            uint2 u1 = *(const uint2*)(emb16 + ((size_t)s_sorted[offB + iB + 4]  << 7) + fb);
            uint2 u2 = *(const uint2*)(emb16 + ((size_t)s_sorted[offB + iB + 8]  << 7) + fb);
            uint2 u3 = *(const uint2*)(emb16 + ((size_t)s_sorted[offB + iB + 12] << 7) + fb);
            float2 f;
            f = __half22float2(*(__half2*)&u0.x); accB.x += f.x; accB.y += f.y;
            f = __half22float2(*(__half2*)&u0.y); accB.z += f.x; accB.w += f.y;
            f = __half22float2(*(__half2*)&u1.x); accB.x += f.x; accB.y += f.y;
            f = __half22float2(*(__half2*)&u1.y); accB.z += f.x; accB.w += f.y;
            f = __half22float2(*(__half2*)&u2.x); accB.x += f.x; accB.y += f.y;
            f = __half22float2(*(__half2*)&u2.y); accB.z += f.x; accB.w += f.y;
            f = __half22float2(*(__half2*)&u3.x); accB.x += f.x; accB.y += f.y;
            f = __half22float2(*(__half2*)&u3.y); accB.z += f.x; accB.w += f.y;
        }
        // tails: up to 6 independent guarded loads, all issued before use
        {
            uint2 a0 = make_uint2(0u, 0u), a1 = a0, a2 = a0;
            uint2 b0 = a0, b1 = a0, b2 = a0;
            if (iA < degA)     a0 = *(const uint2*)(emb16 + ((size_t)s_sorted[offA + iA]     << 7) + fb);
            if (iA + 4 < degA) a1 = *(const uint2*)(emb16 + ((size_t)s_sorted[offA + iA + 4] << 7) + fb);
            if (iA + 8 < degA) a2 = *(const uint2*)(emb16 + ((size_t)s_sorted[offA + iA + 8] << 7) + fb);
            if (iB < degB)     b0 = *(const uint2*)(emb16 + ((size_t)s_sorted[offB + iB]     << 7) + fb);
            if (iB + 4 < degB) b1 = *(const uint2*)(emb16 + ((size_t)s_sorted[offB + iB + 4] << 7) + fb);
            if (iB + 8 < degB) b2 = *(const uint2*)(emb16 + ((size_t)s_sorted[offB + iB + 8] << 7) + fb);
            float2 f;
            f = __half22float2(*(__half2*)&a0.x); accA.x += f.x; accA.y += f.y;
            f = __half22float2(*(__half2*)&a0.y); accA.z += f.x; accA.w += f.y;
            f = __half22float2(*(__half2*)&a1.x); accA.x += f.x; accA.y += f.y;
            f = __half22float2(*(__half2*)&a1.y); accA.z += f.x; accA.w += f.y;
            f = __half22float2(*(__half2*)&a2.x); accA.x += f.x; accA.y += f.y;
            f = __half22float2(*(__half2*)&a2.y); accA.z += f.x; accA.w += f.y;
            f = __half22float2(*(__half2*)&b0.x); accB.x += f.x; accB.y += f.y;
            f = __half22float2(*(__half2*)&b0.y); accB.z += f.x; accB.w += f.y;
            f = __half22float2(*(__half2*)&b1.x); accB.x += f.x; accB.y += f.y;
            f = __half22float2(*(__half2*)&b1.y); accB.z += f.x; accB.w += f.y;
            f = __half22float2(*(__half2*)&b2.x); accB.x += f.x; accB.y += f.y;
            f = __half22float2(*(__half2*)&b2.y); accB.z += f.x; accB.w += f.y;
        }

        // reduce both across the 4 edge subgroups (independent chains)
        #pragma unroll
        for (int m = 16; m < 64; m <<= 1) {
            accA.x += __shfl_xor(accA.x, m);  accB.x += __shfl_xor(accB.x, m);
            accA.y += __shfl_xor(accA.y, m);  accB.y += __shfl_xor(accB.y, m);
            accA.z += __shfl_xor(accA.z, m);  accB.z += __shfl_xor(accB.z, m);
            accA.w += __shfl_xor(accA.w, m);  accB.w += __shfl_xor(accB.w, m);
        }

        if (sub == 0) {
            int nodeA = (b << BIN_SHIFT) + lnA;
            int nodeB = (b << BIN_SHIFT) + lnB;
            float invA = 1.0f / (float)max(degA, 1);
            float invB = 1.0f / (float)max(degB, 1);
            accA.x *= invA; accA.y *= invA; accA.z *= invA; accA.w *= invA;
            accB.x *= invB; accB.y *= invB; accB.z *= invB; accB.w *= invB;
            if (nodeA < N_NODES)
                *(float4*)(out + (size_t)nodeA * D_FEAT + fq * 4) = accA;
            if (nodeB < N_NODES)
                *(float4*)(out + (size_t)nodeB * D_FEAT + fq * 4) = accB;
        }
    }
}

// ======================= Fallback (R1 atomic path) =========================

__global__ void gcn_zero_kernel(float* __restrict__ out, float* __restrict__ counts) {
    int stride = gridDim.x * blockDim.x;
    int i = blockIdx.x * blockDim.x + threadIdx.x;
    const int total = N_NODES * D_FEAT;
    for (int idx = i; idx < total; idx += stride) out[idx] = 0.0f;
    for (int idx = i; idx < N_NODES; idx += stride) counts[idx] = 0.0f;
}

__global__ void gcn_scatter_kernel(const float* __restrict__ emb,
                                   const int* __restrict__ src,
                                   const int* __restrict__ dst,
                                   float* __restrict__ out,
                                   float* __restrict__ counts) {
    int gid  = blockIdx.x * blockDim.x + threadIdx.x;
    int edge = gid >> 6;
    int lane = gid & 63;
    if (edge >= N_EDGES) return;
    int s = src[edge];
    int d = dst[edge];
    float v = emb[(size_t)s * D_FEAT + lane];
    atomicAdd(&out[(size_t)d * D_FEAT + lane], v);
    if (lane == 0) atomicAdd(&counts[d], 1.0f);
}

__global__ void gcn_norm_kernel(float* __restrict__ out,
                                const float* __restrict__ counts) {
    int i = blockIdx.x * blockDim.x + threadIdx.x;
    if (i >= N_NODES * D_FEAT) return;
    int n = i >> 6;
    float c = counts[n];
    out[i] *= (1.0f / fmaxf(c, 1.0f));
}

// ===========================================================================

extern "C" void kernel_launch(void* const* d_in, const int* in_sizes, int n_in,
                              void* d_out, int out_size, void* d_ws, size_t ws_size,
                              hipStream_t stream) {
    const float* emb = (const float*)d_in[0];
    const int*   src = (const int*)d_in[1];
    const int*   dst = (const int*)d_in[2];
    float* out = (float*)d_out;

    if (ws_size >= WS_NEEDED) {
        int* ws = (int*)d_ws;
        prep_kernel<<<NCHUNK, 1024, 0, stream>>>(emb, src, dst, ws);
        fused_gather_kernel<<<NBINS, 512, 0, stream>>>(ws, out);
    } else {
        float* counts = (float*)d_ws;
        gcn_zero_kernel<<<2048, 256, 0, stream>>>(out, counts);
        const int scatter_blocks = (N_EDGES * 64) / 256;
        gcn_scatter_kernel<<<scatter_blocks, 256, 0, stream>>>(emb, src, dst, out, counts);
        const int norm_blocks = (N_NODES * D_FEAT + 255) / 256;
        gcn_norm_kernel<<<norm_blocks, 256, 0, stream>>>(out, counts);
    }
}